// Round 12
// baseline (259.463 us; speedup 1.0000x reference)
//
#include <hip/hip_runtime.h>
#include <stdint.h>

#define BB 4
#define SS 2048
#define DD 512
#define HH 8
#define DKK 64
#define MR (BB*SS)              // 8192 rows
#define NE (MR*DD)              // 4194304 elements per activation matrix
#define NW (DD*DD)              // 262144 per weight

using half8v = __attribute__((ext_vector_type(8))) _Float16;
using half4v = __attribute__((ext_vector_type(4))) _Float16;
using f32x4  = __attribute__((ext_vector_type(4))) float;

__device__ __forceinline__ void gload_lds16(const void* g, void* l) {
    __builtin_amdgcn_global_load_lds((const __attribute__((address_space(1))) void*)g,
                                     (__attribute__((address_space(3))) void*)l, 16, 0, 0);
}

// ---------------------------------------------------------------------------
// Convert 7 fp32 tensors -> fp16. (unchanged, verified)
// ---------------------------------------------------------------------------
struct CvtArgs { const float* s[7]; _Float16* d[7]; };

__global__ __launch_bounds__(256)
void cvt7_f32_f16(CvtArgs a)
{
    const int bid = blockIdx.x;
    int t, lb;
    if      (bid < 2048) { t = 0; lb = bid; }
    else if (bid < 4096) { t = 1; lb = bid - 2048; }
    else if (bid < 6144) { t = 2; lb = bid - 4096; }
    else { const int r = bid - 6144; t = 3 + (r >> 7); lb = r & 127; }
    const float* __restrict__ src = a.s[t];
    _Float16*    __restrict__ dst = a.d[t];
    const int idx = lb * 2048 + threadIdx.x * 8;
    const float4 v0 = *(const float4*)&src[idx];
    const float4 v1 = *(const float4*)&src[idx + 4];
    half8v h;
    h[0] = (_Float16)v0.x; h[1] = (_Float16)v0.y; h[2] = (_Float16)v0.z; h[3] = (_Float16)v0.w;
    h[4] = (_Float16)v1.x; h[5] = (_Float16)v1.y; h[6] = (_Float16)v1.z; h[7] = (_Float16)v1.w;
    *(half8v*)&dst[idx] = h;
}

// ---------------------------------------------------------------------------
// fp16 MFMA GEMM body (unchanged, verified)
// ---------------------------------------------------------------------------
struct QkvPtrs {
    const _Float16* A[3];
    const _Float16* W[3];
    _Float16*       C[3];
};

#define GEMM_BODY(Ag, Wg)                                                      \
    __shared__ _Float16 Ash[128*32];                                           \
    __shared__ _Float16 Wsh[128*32];                                           \
    const int tid = threadIdx.x;                                               \
    const int w = tid >> 6, lane = tid & 63;                                   \
    const int lr = lane & 15, lg = lane >> 4;                                  \
    const int wr = w >> 1, wc = w & 1;                                         \
    const int col0 = blockIdx.x * 128;                                         \
    const int row0 = blockIdx.y * 128;                                         \
    f32x4 acc[4][4];                                                           \
    _Pragma("unroll")                                                          \
    for (int m = 0; m < 4; ++m)                                                \
        _Pragma("unroll")                                                      \
        for (int n = 0; n < 4; ++n) acc[m][n] = (f32x4)0.0f;                   \
    const int srow = lane >> 2;                                                \
    const int sg   = lane & 3;                                                 \
    for (int k0 = 0; k0 < 512; k0 += 32) {                                     \
        if (k0) __syncthreads();                                               \
        _Pragma("unroll")                                                      \
        for (int i = 0; i < 2; ++i) {                                          \
            const int j = w*2 + i;                                             \
            gload_lds16(&Ag[(size_t)(row0 + j*16 + srow)*512 + k0 + sg*8],     \
                        &Ash[j*512]);                                          \
            gload_lds16(&Wg[(size_t)(col0 + j*16 + srow)*512 + k0 + sg*8],     \
                        &Wsh[j*512]);                                          \
        }                                                                      \
        __syncthreads();                                                       \
        half8v af[4], bf[4];                                                   \
        _Pragma("unroll")                                                      \
        for (int m = 0; m < 4; ++m)                                            \
            af[m] = *(const half8v*)&Ash[(wr*64 + m*16 + lr)*32 + lg*8];       \
        _Pragma("unroll")                                                      \
        for (int n = 0; n < 4; ++n)                                            \
            bf[n] = *(const half8v*)&Wsh[(wc*64 + n*16 + lr)*32 + lg*8];       \
        _Pragma("unroll")                                                      \
        for (int m = 0; m < 4; ++m)                                            \
            _Pragma("unroll")                                                  \
            for (int n = 0; n < 4; ++n)                                        \
                acc[m][n] = __builtin_amdgcn_mfma_f32_16x16x32_f16(            \
                                af[m], bf[n], acc[m][n], 0, 0, 0);             \
    }

__global__ __launch_bounds__(256)
void gemm_qkv_f16(QkvPtrs p)
{
    const _Float16* Agp = p.A[blockIdx.z];
    const _Float16* Wgp = p.W[blockIdx.z];
    _Float16*       Cgp = p.C[blockIdx.z];
    GEMM_BODY(Agp, Wgp)
#pragma unroll
    for (int m = 0; m < 4; ++m)
#pragma unroll
    for (int n = 0; n < 4; ++n)
#pragma unroll
    for (int r = 0; r < 4; ++r) {
        const int row = row0 + wr*64 + m*16 + lg*4 + r;
        const int col = col0 + wc*64 + n*16 + lr;
        Cgp[(size_t)row*512 + col] = (_Float16)acc[m][n][r];
    }
}

__global__ __launch_bounds__(256)
void gemm_o_f16(const _Float16* __restrict__ Agp, const _Float16* __restrict__ Wgp,
                const float* __restrict__ bias, float* __restrict__ out)
{
    GEMM_BODY(Agp, Wgp)
#pragma unroll
    for (int m = 0; m < 4; ++m)
#pragma unroll
    for (int n = 0; n < 4; ++n)
#pragma unroll
    for (int r = 0; r < 4; ++r) {
        const int row = row0 + wr*64 + m*16 + lg*4 + r;
        const int col = col0 + wc*64 + n*16 + lr;
        out[(size_t)row*512 + col] = acc[m][n][r] + bias[col];
    }
}

// ---------------------------------------------------------------------------
// Flash attention v2: Q-tile 64 (was 128) -> grid 1024 blocks = 4/CU.
// Round-8 counters showed occupancy 20% (grid-limited at 2 blocks/CU),
// both pipes <50% busy => latency-bound. Per-wave: ONE 16-row stripe.
// Same per-row arithmetic as verified v1 => absmax must stay 9.77e-4.
// LDS 24 KB: K[64][64] + Vt[64][64] + P per-wave [16][64], all fp16,
// 16B-granule XOR swizzle (gran ^= row&7).
// ---------------------------------------------------------------------------
__global__ __launch_bounds__(256, 2)
void flash_attn_f16(const _Float16* __restrict__ Qp, const _Float16* __restrict__ Kp,
                    const _Float16* __restrict__ Vp, const uint8_t* __restrict__ mask,
                    _Float16* __restrict__ Op)
{
    __shared__ _Float16 KsL[64*64];     // 8 KB  [krow][dk] swizzled
    __shared__ _Float16 VtL[64*64];     // 8 KB  [dk][krow] swizzled
    __shared__ _Float16 PsL[4][16*64];  // 8 KB  [qrow][k]  swizzled, per-wave

    const int tid  = threadIdx.x;
    const int w    = tid >> 6;
    const int lane = tid & 63;
    const int lr   = lane & 15;
    const int lg   = lane >> 4;
    const int q0   = blockIdx.x * 64;
    const int h    = blockIdx.y;
    const int b    = blockIdx.z;
    const size_t bS = (size_t)b * SS;

    // ---- Q fragments: wave w owns rows q0 + w*16 + [0,16) ----
    half8v qf[2];
#pragma unroll
    for (int ds = 0; ds < 2; ++ds)
        qf[ds] = *(const half8v*)&Qp[(bS + q0 + w*16 + lr) * DD + h*DKK + ds*32 + lg*8];

    float m_[4], l_[4];
    f32x4 Oc[4];
#pragma unroll
    for (int r = 0; r < 4; ++r) { m_[r] = -1e30f; l_[r] = 0.0f; }
#pragma unroll
    for (int dt = 0; dt < 4; ++dt) Oc[dt] = (f32x4)0.0f;

    // staging geometry (fp16)
    const int krow = tid >> 2;          // K: row 0..63
    const int kg0  = (tid & 3) * 2;     //    two 16B granules kg0, kg0+1
    const int vr0  = (tid & 15) * 4;    // V: 4 rows vr0..vr0+3
    const int vc0  = (tid >> 4) * 4;    //    4 d-cols vc0..vc0+3

    half8v kpre[2];
    half4v vpre[4];
#pragma unroll
    for (int i = 0; i < 2; ++i)
        kpre[i] = *(const half8v*)&Kp[(bS + krow) * DD + h*DKK + (kg0 + i)*8];
#pragma unroll
    for (int j = 0; j < 4; ++j)
        vpre[j] = *(const half4v*)&Vp[(bS + vr0 + j) * DD + h*DKK + vc0];

    for (int it = 0; it < SS/64; ++it) {
        const int k0 = it * 64;
        __syncthreads();   // prior iteration's LDS reads complete

        // ---- stage K (row-major) and V (transposed), swizzled ----
#pragma unroll
        for (int i = 0; i < 2; ++i)
            *(half8v*)&KsL[krow*64 + (((kg0 + i) ^ (krow&7)) * 8)] = kpre[i];
#pragma unroll
        for (int j2 = 0; j2 < 4; ++j2) {
            const int d = vc0 + j2;
            half4v tv;
            tv[0] = vpre[0][j2]; tv[1] = vpre[1][j2];
            tv[2] = vpre[2][j2]; tv[3] = vpre[3][j2];
            *(half4v*)&VtL[d*64 + (((vr0>>3) ^ (d&7))*8 + (vr0&7))] = tv;
        }
        __syncthreads();   // staging visible

        // ---- prefetch next tile ----
        if (it + 1 < SS/64) {
            const int kn = k0 + 64;
#pragma unroll
            for (int i = 0; i < 2; ++i)
                kpre[i] = *(const half8v*)&Kp[(bS + kn + krow) * DD + h*DKK + (kg0 + i)*8];
#pragma unroll
            for (int j = 0; j < 4; ++j)
                vpre[j] = *(const half4v*)&Vp[(bS + kn + vr0 + j) * DD + h*DKK + vc0];
        }

        // ---- mask addends for this lane's 4 key columns ----
        float madd[4];
#pragma unroll
        for (int t = 0; t < 4; ++t)
            madd[t] = mask[bS + k0 + t*16 + lr] ? -INFINITY : 0.0f;

        // ---- K B-fragments ----
        half8v kfb[4][2];
#pragma unroll
        for (int t = 0; t < 4; ++t)
#pragma unroll
        for (int ds = 0; ds < 2; ++ds) {
            const int row = t*16 + lr;
            kfb[t][ds] = *(const half8v*)&KsL[row*64 + (((ds*4 + lg) ^ (row&7)) * 8)];
        }

        // ---- QK^T + online softmax ----
        f32x4 sc[4];
#pragma unroll
        for (int t = 0; t < 4; ++t) {
            sc[t] = (f32x4)0.0f;
            sc[t] = __builtin_amdgcn_mfma_f32_16x16x32_f16(qf[0], kfb[t][0], sc[t], 0, 0, 0);
            sc[t] = __builtin_amdgcn_mfma_f32_16x16x32_f16(qf[1], kfb[t][1], sc[t], 0, 0, 0);
        }
        float ss[4][4];
#pragma unroll
        for (int t = 0; t < 4; ++t)
#pragma unroll
        for (int r = 0; r < 4; ++r) ss[t][r] = fmaf(sc[t][r], 0.125f, madd[t]);

        float fac[4];
#pragma unroll
        for (int r = 0; r < 4; ++r) {
            float tm = fmaxf(fmaxf(ss[0][r], ss[1][r]), fmaxf(ss[2][r], ss[3][r]));
#pragma unroll
            for (int off = 1; off <= 8; off <<= 1) tm = fmaxf(tm, __shfl_xor(tm, off));
            const float mn = fmaxf(m_[r], tm);
            const float fc = __expf(m_[r] - mn);
            m_[r] = mn;
            float lsum = 0.0f;
#pragma unroll
            for (int t = 0; t < 4; ++t) {
                const float p = __expf(ss[t][r] - mn);
                ss[t][r] = p;
                lsum += p;
            }
#pragma unroll
            for (int off = 1; off <= 8; off <<= 1) lsum += __shfl_xor(lsum, off);
            l_[r] = l_[r] * fc + lsum;
            fac[r] = fc;
        }

        // ---- P -> per-wave LDS (fp16), granule swizzle ----
#pragma unroll
        for (int t = 0; t < 4; ++t)
#pragma unroll
        for (int r = 0; r < 4; ++r) {
            const int qrow = lg*4 + r;
            const int k = t*16 + lr;
            PsL[w][qrow*64 + (((k>>3) ^ (qrow&7))*8 + (k&7))] = (_Float16)ss[t][r];
        }

        // ---- rescale O ----
#pragma unroll
        for (int dt = 0; dt < 4; ++dt)
#pragma unroll
        for (int r = 0; r < 4; ++r) Oc[dt][r] *= fac[r];

        // ---- PV ----
        half8v pf[2];
#pragma unroll
        for (int ks = 0; ks < 2; ++ks)
            pf[ks] = *(const half8v*)&PsL[w][lr*64 + (((ks*4 + lg) ^ (lr&7)) * 8)];
        half8v vfb[4][2];
#pragma unroll
        for (int dt = 0; dt < 4; ++dt)
#pragma unroll
        for (int ks = 0; ks < 2; ++ks) {
            const int d = dt*16 + lr;
            vfb[dt][ks] = *(const half8v*)&VtL[d*64 + (((ks*4 + lg) ^ (d&7)) * 8)];
        }
#pragma unroll
        for (int dt = 0; dt < 4; ++dt) {
            Oc[dt] = __builtin_amdgcn_mfma_f32_16x16x32_f16(pf[0], vfb[dt][0], Oc[dt], 0, 0, 0);
            Oc[dt] = __builtin_amdgcn_mfma_f32_16x16x32_f16(pf[1], vfb[dt][1], Oc[dt], 0, 0, 0);
        }
    }

    // ---- epilogue: normalize, store fp16 [b,s,h,dk] ----
#pragma unroll
    for (int r = 0; r < 4; ++r) {
        const float inv = (l_[r] > 0.0f) ? (1.0f / l_[r]) : 0.0f;
        const int q = q0 + w*16 + lg*4 + r;
#pragma unroll
        for (int dt = 0; dt < 4; ++dt)
            Op[(bS + q) * DD + h*DKK + dt*16 + lr] = (_Float16)(Oc[dt][r] * inv);
    }
}

// ---------------------------------------------------------------------------
extern "C" void kernel_launch(void* const* d_in, const int* in_sizes, int n_in,
                              void* d_out, int out_size, void* d_ws, size_t ws_size,
                              hipStream_t stream)
{
    const float*   query = (const float*)d_in[0];
    const float*   key   = (const float*)d_in[1];
    const float*   value = (const float*)d_in[2];
    const uint8_t* mask  = (const uint8_t*)d_in[3];
    const float*   Wq    = (const float*)d_in[4];
    const float*   Wk    = (const float*)d_in[5];
    const float*   Wv    = (const float*)d_in[6];
    const float*   Wo    = (const float*)d_in[7];
    const float*   bo    = (const float*)d_in[8];
    float*         out   = (float*)d_out;

    _Float16* wsh = (_Float16*)d_ws;
    _Float16* qh  = wsh;                 // converted inputs
    _Float16* kh  = qh  + NE;
    _Float16* vh  = kh  + NE;
    _Float16* wqh = vh  + NE;            // converted weights
    _Float16* wkh = wqh + NW;
    _Float16* wvh = wkh + NW;
    _Float16* woh = wvh + NW;
    _Float16* Qh  = woh + NW;            // projected Q/K/V
    _Float16* Kh  = Qh  + NE;
    _Float16* Vh  = Kh  + NE;
    _Float16* Oh  = Vh  + NE;            // attention output

    CvtArgs ca;
    ca.s[0] = query; ca.s[1] = key; ca.s[2] = value;
    ca.s[3] = Wq; ca.s[4] = Wk; ca.s[5] = Wv; ca.s[6] = Wo;
    ca.d[0] = qh; ca.d[1] = kh; ca.d[2] = vh;
    ca.d[3] = wqh; ca.d[4] = wkh; ca.d[5] = wvh; ca.d[6] = woh;
    cvt7_f32_f16<<<6656, 256, 0, stream>>>(ca);

    QkvPtrs gp;
    gp.A[0] = qh;  gp.A[1] = kh;  gp.A[2] = vh;
    gp.W[0] = wqh; gp.W[1] = wkh; gp.W[2] = wvh;
    gp.C[0] = Qh;  gp.C[1] = Kh;  gp.C[2] = Vh;
    gemm_qkv_f16<<<dim3(DD/128, MR/128, 3), 256, 0, stream>>>(gp);

    flash_attn_f16<<<dim3(SS/64, HH, BB), 256, 0, stream>>>(Qh, Kh, Vh, mask, Oh);

    gemm_o_f16<<<dim3(DD/128, MR/128), 256, 0, stream>>>(Oh, woh, bo, out);
}